// Round 9
// baseline (200.838 us; speedup 1.0000x reference)
//
#include <hip/hip_runtime.h>
#include <hip/hip_fp16.h>

// GCN 2-layer. count (+rank) -> multi-block shfl-scan (fused rsqrt, + W2->fp16
// convert in a spare block) -> [fused CSR fill || scan_fix || MFMA gemm1] ->
// [fused agg128+gemm2, B from global] -> agg64.
// out[i] = dis[i]*(scaled[i] + sum_j scaled[j]) + b, scaled[j]=dis[j]*(x@W)[j]
//
// r21 = r20 with the w2h layout bug fixed: gemm2 K=128 (W2 is [128,64]);
// r20 converted only k<64 ([64][64] layout) so B-fragments for k>=64 read
// the next column's data -> absmax 0.319. Now w2h[nn*128+k], 16KB.
// r20 theory (UNTESTED, carried): 32KB-LDS fusions capped the latency-bound
// fill/gather ranges at 4 blk/CU; fill was last in grid so it never
// overlapped gemm1. (1) agg_gemm: no W2 LDS stage -> 16KB LDS +
// launch_bounds(256,6) -> 24 waves/CU; (2) gemm1 N-split 2x64 cols ->
// k_fused 16KB; fill range FIRST.
// r18 POST-MORTEM: coop grid.sync ~100us each on 8-XCD — never again.
// r19: csr-index software pipelining neutral; kept (harmless).
// History: r12 = 203us; r13/r14 sliced agg 264us (gather cost ~ unique
// lines, tier-independent); r15 fill-fuse 202us; r16/r17 agg+gemm2 fuse
// 199us (best); r19 200.7us; r20 FAILED (w2h K-truncation).

typedef _Float16 half8 __attribute__((ext_vector_type(8)));
typedef float floatx4 __attribute__((ext_vector_type(4)));

__global__ void k_count(const int* __restrict__ col, int* __restrict__ deg,
                        int* __restrict__ rank, int E) {
    int e = blockIdx.x * blockDim.x + threadIdx.x;
    if (e < E) rank[e] = atomicAdd(&deg[col[e]], 1);
}

// Per-chunk inclusive scan via wave shfl (2 barriers) + dis = rsqrt(deg+1).
// Writes rowptr (to be globally fixed) AND praw (raw copy for the fused
// fill). Last block (b == gridDim-1) instead converts W2 -> fp16 w2h in
// B-fragment layout w2h[nn*128 + k] = W2[k][nn] (16KB, L1/L2-resident).
__global__ __launch_bounds__(1024) void k_scan_local(const int* __restrict__ deg,
                                                     int* __restrict__ rowptr,
                                                     int* __restrict__ praw,
                                                     int* __restrict__ bsum,
                                                     float* __restrict__ dis, int n,
                                                     const float* __restrict__ W2,
                                                     __half* __restrict__ w2h) {
    __shared__ int wsum[16];
    int b = blockIdx.x, tid = threadIdx.x;
    if (b == gridDim.x - 1) {
        for (int i = tid; i < 64 * 128; i += 1024) {
            int nn = i >> 7, k = i & 127;  // w2h[nn][k] = W2[k][nn], K=128
            w2h[i] = __float2half(W2[(size_t)k * 64 + nn]);
        }
        return;
    }
    int lane = tid & 63, w = tid >> 6;
    int i = b * 1024 + tid;
    int v = (i < n) ? deg[i] : 0;
    if (i < n) dis[i] = rsqrtf((float)v + 1.0f);  // +1 = self-loop
    int sc = v;
#pragma unroll
    for (int off = 1; off < 64; off <<= 1) {
        int t = __shfl_up(sc, off);
        if (lane >= off) sc += t;
    }
    if (lane == 63) wsum[w] = sc;
    __syncthreads();
    if (w == 0) {
        int s = (lane < 16) ? wsum[lane] : 0;
#pragma unroll
        for (int off = 1; off < 16; off <<= 1) {
            int t = __shfl_up(s, off);
            if (lane >= off) s += t;
        }
        if (lane < 16) wsum[lane] = s;
    }
    __syncthreads();
    int incl = sc + ((w > 0) ? wsum[w - 1] : 0);
    if (i < n) {
        rowptr[i + 1] = incl;
        praw[i + 1] = incl;
    }
    if (tid == 1023) bsum[b] = incl;
    if (b == 0 && tid == 0) {
        rowptr[0] = 0;
        praw[0] = 0;
    }
}

// One 64-row x 64-col half-tile of Y[M,128] = (X[M,128] @ W1) * scale[m].
// Stages the nh-th 64-col slab of W1 as fp16 in LDS (16KB, XOR-swizzled
// <=2-way banks). Frags (m89/m118/m120): A[m=lane&15][k=quad*8+j],
// B[k][n=lane&15], D row=quad*4+reg, col=lane&15.
__device__ __forceinline__ void gemm1_half(const float* __restrict__ X,
                                           const float* __restrict__ W1,
                                           const float* __restrict__ scale,
                                           __half* __restrict__ Y, int M,
                                           int m0, int nh, __half2* wt, int tid) {
    for (int i = tid; i < 64 * 64; i += 256) {
        int nn = i & 63;
        int k2 = i >> 6;  // k = 2*k2, 0..126
        float w0 = W1[(size_t)(2 * k2) * 128 + nh * 64 + nn];
        float w1 = W1[(size_t)(2 * k2 + 1) * 128 + nh * 64 + nn];
        wt[nn * 64 + ((k2 >> 2) ^ (nn & 15)) * 4 + (k2 & 3)] = __floats2half2_rn(w0, w1);
    }
    __syncthreads();
    int wid = tid >> 6, lane = tid & 63;
    int col = lane & 15, quad = lane >> 4;
    int m_a = m0 + wid * 16 + col;
    bool a_ok = m_a < M;
    floatx4 acc[4] = {};
#pragma unroll
    for (int ks = 0; ks < 4; ++ks) {
        int k = ks * 32 + quad * 8;
        floatx4 a0 = {0.f, 0.f, 0.f, 0.f}, a1 = {0.f, 0.f, 0.f, 0.f};
        if (a_ok) {
            a0 = *(const floatx4*)&X[(size_t)m_a * 128 + k];
            a1 = *(const floatx4*)&X[(size_t)m_a * 128 + k + 4];
        }
        half8 af = half8{(_Float16)a0[0], (_Float16)a0[1], (_Float16)a0[2], (_Float16)a0[3],
                         (_Float16)a1[0], (_Float16)a1[1], (_Float16)a1[2], (_Float16)a1[3]};
        int kblk = ks * 4 + quad;
#pragma unroll
        for (int nt = 0; nt < 4; ++nt) {
            int nn = nt * 16 + col;
            half8 bf = *(const half8*)(const void*)&wt[nn * 64 + (kblk ^ (nn & 15)) * 4];
            acc[nt] = __builtin_amdgcn_mfma_f32_16x16x32_f16(af, bf, acc[nt], 0, 0, 0);
        }
    }
    int mbase = m0 + wid * 16 + quad * 4;
    float s[4];
#pragma unroll
    for (int r = 0; r < 4; ++r) s[r] = (mbase + r < M) ? scale[mbase + r] : 0.f;
#pragma unroll
    for (int nt = 0; nt < 4; ++nt) {
#pragma unroll
        for (int r = 0; r < 4; ++r) {
            if (mbase + r < M)
                Y[(size_t)(mbase + r) * 128 + nh * 64 + nt * 16 + col] =
                    __float2half(acc[nt][r] * s[r]);
        }
    }
}

// Fused 3-range kernel (16KB LDS -> up to 8 blocks/CU for every range):
//   blocks [0,FILLB):        CSR fill — pos = praw[c] + Q[(c-1)>>10] + rank[e]
//                            (FIRST so the scatter co-resides with gemm1)
//   blocks [FILLB,FILLB+FB): scan_fix — add chunk prefix to rowptr
//   blocks [FILLB+FB,...):   gemm1, N-split: block pair (t, nh=gb&1)
__global__ __launch_bounds__(256) void k_fused(int* __restrict__ rowptr,
                                               const int* __restrict__ bsum, int n,
                                               const float* __restrict__ X,
                                               const float* __restrict__ W1,
                                               const float* __restrict__ scale,
                                               __half* __restrict__ Y, int M,
                                               int FB, int FILLB,
                                               const int* __restrict__ praw,
                                               const int* __restrict__ row,
                                               const int* __restrict__ col,
                                               const int* __restrict__ rank,
                                               int* __restrict__ csr, int E) {
    __shared__ __align__(16) __half2 wt[64 * 64];  // 16 KB; reused by fix/fill
    int b = blockIdx.x, tid = threadIdx.x;
    if (b < FILLB) {
        // ---- fill range: 1024 edges per block ----
        int* q = (int*)wt;  // Q[l] = sum bsum[0..l-1], l in [0,63]
        int nb = (n + 1023) >> 10;  // chunk count (<=49 here, <=64 supported)
        if (tid < 64) {
            int v = (tid >= 1 && tid <= nb) ? bsum[tid - 1] : 0;
#pragma unroll
            for (int off = 1; off < 64; off <<= 1) {
                int t = __shfl_up(v, off);
                if ((tid & 63) >= off) v += t;
            }
            q[tid] = v;  // inclusive scan of shifted bsum == exclusive prefix Q
        }
        __syncthreads();
        int base = b * 1024;
#pragma unroll
        for (int r = 0; r < 4; ++r) {
            int e = base + r * 256 + tid;
            if (e < E) {
                int c = col[e];
                int qi = (c == 0) ? 0 : ((c - 1) >> 10);  // praw[0]=0, Q[0]=0
                csr[praw[c] + q[qi] + rank[e]] = row[e];
            }
        }
        return;
    }
    if (b < FILLB + FB) {
        int bb = b - FILLB;
        int* red = (int*)wt;
        int partial = 0;
        for (int j = tid; j < bb; j += 256) partial += bsum[j];
        red[tid] = partial;
        __syncthreads();
        for (int off = 128; off > 0; off >>= 1) {
            if (tid < off) red[tid] += red[tid + off];
            __syncthreads();
        }
        int offv = red[0];
        if (offv == 0) return;
#pragma unroll
        for (int r = 0; r < 4; ++r) {
            int i = bb * 1024 + r * 256 + tid;
            if (i < n) rowptr[i + 1] += offv;
        }
        return;
    }
    int gb = b - FILLB - FB;
    gemm1_half(X, W1, scale, Y, M, (gb >> 1) * 64, gb & 1, wt, tid);
}

// Fused agg128 + gemm2. Block = 64 nodes (4 agg sub-phases of 16 nodes),
// then xw2[64,64] = (h_tile @ W2) * dis via MFMA.
// Agg: 4 nodes/wave (quad per node; 16 lanes x 16B = one 256B row per
// gather instr), cooperative csr load pipelined one iter ahead (r19).
// h_tile row m LDS XOR swizzle slot^=(m&7). gemm2 B-fragments read from
// global w2h[nn*128+k] (16KB, L1-resident) — no LDS stage -> 16KB LDS.
__global__ __launch_bounds__(256, 6) void k_agg_gemm(const __half* __restrict__ xw,
                                                     const float* __restrict__ dis,
                                                     const int* __restrict__ rowptr,
                                                     const int* __restrict__ csr,
                                                     const float* __restrict__ bias,
                                                     const __half* __restrict__ w2h,
                                                     __half* __restrict__ Y,  // xw2 [n,64]
                                                     int n) {
    __shared__ __align__(16) half8 htile[64 * 16];   // 16 KB
    int tid = threadIdx.x, b = blockIdx.x;
    int lane = tid & 63, w = tid >> 6;
    int q = lane >> 4, li = lane & 15;
    int qbase = lane & 48;

    const half8* rows = (const half8*)xw;  // 16 half8 per row
    floatx4 bb0 = *(const floatx4*)&bias[li * 8];
    floatx4 bb1 = *(const floatx4*)&bias[li * 8 + 4];

#pragma unroll
    for (int g = 0; g < 4; ++g) {
        int m_loc = g * 16 + (w << 2) + q;     // local row 0..63
        int node = b * 64 + m_loc;
        bool ok = node < n;
        float di = 0.f;
        int beg = 0, end = 0;
        if (ok) {
            di = dis[node];
            beg = rowptr[node];
            end = rowptr[node + 1];
        }
        int dg = end - beg;
        int m1 = max(dg, __shfl(dg, lane ^ 16));
        int mx = max(m1, __shfl(m1, lane ^ 32));  // max over the wave's 4 nodes
        float acc[8] = {};
        if (ok) {
            half8 sf = rows[(size_t)node * 16 + li];
#pragma unroll
            for (int f = 0; f < 8; ++f) acc[f] = (float)sf[f];
        }
        // software-pipelined csr index load (one iteration ahead)
        int ecur = beg + (li & 7);
        int curidx = (0 < mx && ecur < end) ? csr[ecur] : 0;
        for (int i = 0; i < mx; i += 8) {
            int enx = beg + i + 8 + (li & 7);
            int nidx = (i + 8 < mx && enx < end) ? csr[enx] : 0;
            half8 v[8];
#pragma unroll
            for (int j = 0; j < 8; ++j) {
                int s = __shfl(curidx, qbase + j);
                v[j] = rows[(size_t)s * 16 + li];
            }
#pragma unroll
            for (int j = 0; j < 8; ++j) {
                if (beg + i + j < end) {
#pragma unroll
                    for (int f = 0; f < 8; ++f) acc[f] += (float)v[j][f];
                }
            }
            curidx = nidx;
        }
        half8 o = {};
        if (ok) {
#pragma unroll
            for (int f = 0; f < 4; ++f) o[f] = (_Float16)fmaxf(acc[f] * di + bb0[f], 0.f);
#pragma unroll
            for (int f = 0; f < 4; ++f) o[4 + f] = (_Float16)fmaxf(acc[4 + f] * di + bb1[f], 0.f);
        }
        htile[m_loc * 16 + (li ^ (m_loc & 7))] = o;
    }
    __syncthreads();

    // GEMM phase: A from htile (swizzled), B from global w2h (L1-resident).
    int col16 = lane & 15, quad = lane >> 4;
    int m_loc = w * 16 + col16;
    floatx4 gacc[4] = {};
#pragma unroll
    for (int ks = 0; ks < 4; ++ks) {
        half8 af = htile[m_loc * 16 + ((ks * 4 + quad) ^ (m_loc & 7))];
        int kblk = ks * 4 + quad;
#pragma unroll
        for (int nt = 0; nt < 4; ++nt) {
            int nn = nt * 16 + col16;
            half8 bf = *(const half8*)(const void*)&w2h[nn * 128 + kblk * 8];
            gacc[nt] = __builtin_amdgcn_mfma_f32_16x16x32_f16(af, bf, gacc[nt], 0, 0, 0);
        }
    }
    int mbase = b * 64 + w * 16 + quad * 4;
    float s[4];
#pragma unroll
    for (int r = 0; r < 4; ++r) s[r] = (mbase + r < n) ? dis[mbase + r] : 0.f;
#pragma unroll
    for (int nt = 0; nt < 4; ++nt) {
#pragma unroll
        for (int r = 0; r < 4; ++r) {
            if (mbase + r < n)
                Y[(size_t)(mbase + r) * 64 + nt * 16 + col16] = __float2half(gacc[nt][r] * s[r]);
        }
    }
}

// F=64: 8 nodes/wave (8 lanes x 16B = one 128B row per gather instr).
// csr index load software-pipelined one iteration ahead (r19).
__global__ __launch_bounds__(256) void k_agg64(const __half* __restrict__ xw,
                                               const float* __restrict__ dis,
                                               const int* __restrict__ rowptr,
                                               const int* __restrict__ csr,
                                               const float* __restrict__ bias,
                                               float* __restrict__ out, int n) {
    int tid = threadIdx.x;
    int lane = tid & 63;
    int o8 = lane >> 3, li = lane & 7;
    int obase = lane & 56;
    int node = blockIdx.x * 32 + ((tid >> 6) << 3) + o8;
    bool ok = node < n;
    float di = 0.f;
    int beg = 0, end = 0;
    if (ok) {
        di = dis[node];
        beg = rowptr[node];
        end = rowptr[node + 1];
    }
    int dg = end - beg;
    int m1 = max(dg, __shfl(dg, lane ^ 8));
    int m2 = max(m1, __shfl(m1, lane ^ 16));
    int mx = max(m2, __shfl(m2, lane ^ 32));  // max over the wave's 8 nodes
    const half8* rows = (const half8*)xw;     // 8 half8 per row
    float acc[8] = {};
    if (ok) {
        half8 sf = rows[(size_t)node * 8 + li];
#pragma unroll
        for (int f = 0; f < 8; ++f) acc[f] = (float)sf[f];
    }
    int ecur = beg + li;
    int curidx = (0 < mx && ecur < end) ? csr[ecur] : 0;
    for (int i = 0; i < mx; i += 8) {
        int enx = beg + i + 8 + li;
        int nidx = (i + 8 < mx && enx < end) ? csr[enx] : 0;
        half8 v[8];
#pragma unroll
        for (int j = 0; j < 8; ++j) {
            int s = __shfl(curidx, obase + j);
            v[j] = rows[(size_t)s * 8 + li];
        }
#pragma unroll
        for (int j = 0; j < 8; ++j) {
            if (beg + i + j < end) {
#pragma unroll
                for (int f = 0; f < 8; ++f) acc[f] += (float)v[j][f];
            }
        }
        curidx = nidx;
    }
    if (ok) {
        floatx4 b0 = *(const floatx4*)&bias[li * 8];
        floatx4 b1 = *(const floatx4*)&bias[li * 8 + 4];
        floatx4 o0, o1;
#pragma unroll
        for (int f = 0; f < 4; ++f) o0[f] = acc[f] * di + b0[f];
#pragma unroll
        for (int f = 0; f < 4; ++f) o1[f] = acc[4 + f] * di + b1[f];
        *(floatx4*)&out[(size_t)node * 64 + li * 8] = o0;
        *(floatx4*)&out[(size_t)node * 64 + li * 8 + 4] = o1;
    }
}

extern "C" void kernel_launch(void* const* d_in, const int* in_sizes, int n_in,
                              void* d_out, int out_size, void* d_ws, size_t ws_size,
                              hipStream_t stream) {
    const float* x  = (const float*)d_in[0];
    const int*   ei = (const int*)d_in[1];
    const float* W1 = (const float*)d_in[2];
    const float* b1 = (const float*)d_in[3];
    const float* W2 = (const float*)d_in[4];
    const float* b2 = (const float*)d_in[5];
    float* out = (float*)d_out;

    const int n = in_sizes[0] / 128;   // 50000
    const int E = in_sizes[1] / 2;     // 800000
    const int* row = ei;
    const int* col = ei + E;
    const int NB = (n + 1023) / 1024;       // scan chunks (fix range)
    const int CB = (E + 255) / 256;
    const int GB = (n + 63) / 64;           // agg_gemm blocks; gemm1 = 2*GB
    const int FILLB = (E + 1023) / 1024;    // fused fill blocks (1024 edges each)

    char* ws = (char*)d_ws;
    size_t off = 0;
    auto alloc = [&](size_t bytes) -> void* {
        void* p = ws + off;
        off += (bytes + 255) & ~(size_t)255;
        return p;
    };
    int*    deg    = (int*)alloc((size_t)n * 4);
    int*    rowptr = (int*)alloc((size_t)(n + 1) * 4);
    int*    praw   = (int*)alloc((size_t)(n + 1) * 4);
    int*    bsum   = (int*)alloc((size_t)NB * 4);
    int*    rank   = (int*)alloc((size_t)E * 4);
    int*    csr    = (int*)alloc((size_t)E * 4);
    float*  dis    = (float*)alloc((size_t)n * 4);
    __half* xw1    = (__half*)alloc((size_t)n * 128 * 2);
    __half* xw2    = (__half*)alloc((size_t)n * 64 * 2);
    __half* w2h    = (__half*)alloc((size_t)64 * 128 * 2);  // [64 cols][128 k]
    (void)ws_size;

    hipMemsetAsync(deg, 0, (size_t)n * 4, stream);
    k_count<<<CB, 256, 0, stream>>>(col, deg, rank, E);
    // scan (NB blocks) + 1 spare block converting W2 -> fp16 w2h
    k_scan_local<<<NB + 1, 1024, 0, stream>>>(deg, rowptr, praw, bsum, dis, n, W2, w2h);
    // fill || fix || gemm1 (N-split) in one 16KB-LDS dispatch; fill first.
    k_fused<<<FILLB + NB + 2 * GB, 256, 0, stream>>>(rowptr, bsum, n, x, W1, dis, xw1,
                                                     n, NB, FILLB, praw, row, col, rank,
                                                     csr, E);
    // agg128 + gemm2 fused: h never touches HBM; B from global w2h.
    k_agg_gemm<<<GB, 256, 0, stream>>>(xw1, dis, rowptr, csr, b1, w2h, xw2, n);
    k_agg64<<<(n + 31) / 32, 256, 0, stream>>>(xw2, dis, rowptr, csr, b2, out, n);
}

// Round 10
// 198.106 us; speedup vs baseline: 1.0138x; 1.0138x over previous
//
#include <hip/hip_runtime.h>
#include <hip/hip_fp16.h>

// GCN 2-layer. count (+rank) -> multi-block shfl-scan (fused rsqrt; spare
// block converts W2->fp16 + zeroes the zero-rows) -> [fused CSR fill ||
// scan_fix || MFMA gemm1] -> [fused agg128+gemm2] -> agg64.
// out[i] = dis[i]*(scaled[i] + sum_j scaled[j]) + b, scaled[j]=dis[j]*(x@W)[j]
//
// r22: agg VALU-diet. Falsified so far for the agg floor: serving tier
// (r14), csr-index latency (r19), occupancy (r21), launch boundaries
// (r15-r17: <=3us each). Remaining attackable term: r14 showed VALUBusy 48%
// alongside the ~6.4cy/64B-line VMEM floor -> partial VALU/memory
// serialization. Changes: (1) zero-row trick — xw1/xw2 get a zeroed row n;
// invalid edges gather row n instead of being guarded (no divergent
// per-edge branch); (2) packed-fp16 pairwise pre-add (v_pk_add_f16) then
// fp32 accumulate: ~16 -> ~10 VALU ops/edge/lane. One fp16 pre-round per
// pair, error <=2^-11 rel (absmax headroom 3.2x).
// r18 POST-MORTEM: coop grid.sync ~100us each on 8-XCD — never again.
// History: r12 = 203us; r13/r14 sliced agg 264us (line-touch floor,
// tier-independent); r15 fill-fuse 202; r16/r17 agg+gemm2 fuse 199 (best);
// r19 csr-pipelining 200.7 (kept, harmless); r20 FAILED (w2h K-trunc);
// r21 = r20-fixed, occupancy-restore 200.8 (falsified).

typedef _Float16 half8 __attribute__((ext_vector_type(8)));
typedef float floatx4 __attribute__((ext_vector_type(4)));

__global__ void k_count(const int* __restrict__ col, int* __restrict__ deg,
                        int* __restrict__ rank, int E) {
    int e = blockIdx.x * blockDim.x + threadIdx.x;
    if (e < E) rank[e] = atomicAdd(&deg[col[e]], 1);
}

// Per-chunk inclusive scan via wave shfl (2 barriers) + dis = rsqrt(deg+1).
// Writes rowptr (to be globally fixed) AND praw (raw copy for the fused
// fill). Last block instead: converts W2 -> fp16 w2h (B-fragment layout
// w2h[nn*128+k] = W2[k][nn], 16KB) and zeroes xw1 row n + xw2 row n.
__global__ __launch_bounds__(1024) void k_scan_local(const int* __restrict__ deg,
                                                     int* __restrict__ rowptr,
                                                     int* __restrict__ praw,
                                                     int* __restrict__ bsum,
                                                     float* __restrict__ dis, int n,
                                                     const float* __restrict__ W2,
                                                     __half* __restrict__ w2h,
                                                     __half* __restrict__ xw1,
                                                     __half* __restrict__ xw2) {
    __shared__ int wsum[16];
    int b = blockIdx.x, tid = threadIdx.x;
    if (b == gridDim.x - 1) {
        for (int i = tid; i < 64 * 128; i += 1024) {
            int nn = i >> 7, k = i & 127;  // w2h[nn][k] = W2[k][nn], K=128
            w2h[i] = __float2half(W2[(size_t)k * 64 + nn]);
        }
        if (tid < 128) xw1[(size_t)n * 128 + tid] = __float2half(0.f);  // zero row
        else if (tid < 192) xw2[(size_t)n * 64 + (tid - 128)] = __float2half(0.f);
        return;
    }
    int lane = tid & 63, w = tid >> 6;
    int i = b * 1024 + tid;
    int v = (i < n) ? deg[i] : 0;
    if (i < n) dis[i] = rsqrtf((float)v + 1.0f);  // +1 = self-loop
    int sc = v;
#pragma unroll
    for (int off = 1; off < 64; off <<= 1) {
        int t = __shfl_up(sc, off);
        if (lane >= off) sc += t;
    }
    if (lane == 63) wsum[w] = sc;
    __syncthreads();
    if (w == 0) {
        int s = (lane < 16) ? wsum[lane] : 0;
#pragma unroll
        for (int off = 1; off < 16; off <<= 1) {
            int t = __shfl_up(s, off);
            if (lane >= off) s += t;
        }
        if (lane < 16) wsum[lane] = s;
    }
    __syncthreads();
    int incl = sc + ((w > 0) ? wsum[w - 1] : 0);
    if (i < n) {
        rowptr[i + 1] = incl;
        praw[i + 1] = incl;
    }
    if (tid == 1023) bsum[b] = incl;
    if (b == 0 && tid == 0) {
        rowptr[0] = 0;
        praw[0] = 0;
    }
}

// One 64-row x 64-col half-tile of Y[M,128] = (X[M,128] @ W1) * scale[m].
// Stages the nh-th 64-col slab of W1 as fp16 in LDS (16KB, XOR-swizzled
// <=2-way banks). Frags (m89/m118/m120): A[m=lane&15][k=quad*8+j],
// B[k][n=lane&15], D row=quad*4+reg, col=lane&15.
__device__ __forceinline__ void gemm1_half(const float* __restrict__ X,
                                           const float* __restrict__ W1,
                                           const float* __restrict__ scale,
                                           __half* __restrict__ Y, int M,
                                           int m0, int nh, __half2* wt, int tid) {
    for (int i = tid; i < 64 * 64; i += 256) {
        int nn = i & 63;
        int k2 = i >> 6;  // k = 2*k2, 0..126
        float w0 = W1[(size_t)(2 * k2) * 128 + nh * 64 + nn];
        float w1 = W1[(size_t)(2 * k2 + 1) * 128 + nh * 64 + nn];
        wt[nn * 64 + ((k2 >> 2) ^ (nn & 15)) * 4 + (k2 & 3)] = __floats2half2_rn(w0, w1);
    }
    __syncthreads();
    int wid = tid >> 6, lane = tid & 63;
    int col = lane & 15, quad = lane >> 4;
    int m_a = m0 + wid * 16 + col;
    bool a_ok = m_a < M;
    floatx4 acc[4] = {};
#pragma unroll
    for (int ks = 0; ks < 4; ++ks) {
        int k = ks * 32 + quad * 8;
        floatx4 a0 = {0.f, 0.f, 0.f, 0.f}, a1 = {0.f, 0.f, 0.f, 0.f};
        if (a_ok) {
            a0 = *(const floatx4*)&X[(size_t)m_a * 128 + k];
            a1 = *(const floatx4*)&X[(size_t)m_a * 128 + k + 4];
        }
        half8 af = half8{(_Float16)a0[0], (_Float16)a0[1], (_Float16)a0[2], (_Float16)a0[3],
                         (_Float16)a1[0], (_Float16)a1[1], (_Float16)a1[2], (_Float16)a1[3]};
        int kblk = ks * 4 + quad;
#pragma unroll
        for (int nt = 0; nt < 4; ++nt) {
            int nn = nt * 16 + col;
            half8 bf = *(const half8*)(const void*)&wt[nn * 64 + (kblk ^ (nn & 15)) * 4];
            acc[nt] = __builtin_amdgcn_mfma_f32_16x16x32_f16(af, bf, acc[nt], 0, 0, 0);
        }
    }
    int mbase = m0 + wid * 16 + quad * 4;
    float s[4];
#pragma unroll
    for (int r = 0; r < 4; ++r) s[r] = (mbase + r < M) ? scale[mbase + r] : 0.f;
#pragma unroll
    for (int nt = 0; nt < 4; ++nt) {
#pragma unroll
        for (int r = 0; r < 4; ++r) {
            if (mbase + r < M)
                Y[(size_t)(mbase + r) * 128 + nh * 64 + nt * 16 + col] =
                    __float2half(acc[nt][r] * s[r]);
        }
    }
}

// Fused 3-range kernel (16KB LDS):
//   blocks [0,FILLB):        CSR fill (FIRST: co-resides with gemm1)
//   blocks [FILLB,FILLB+FB): scan_fix
//   blocks [FILLB+FB,...):   gemm1, N-split (t, nh=gb&1)
__global__ __launch_bounds__(256) void k_fused(int* __restrict__ rowptr,
                                               const int* __restrict__ bsum, int n,
                                               const float* __restrict__ X,
                                               const float* __restrict__ W1,
                                               const float* __restrict__ scale,
                                               __half* __restrict__ Y, int M,
                                               int FB, int FILLB,
                                               const int* __restrict__ praw,
                                               const int* __restrict__ row,
                                               const int* __restrict__ col,
                                               const int* __restrict__ rank,
                                               int* __restrict__ csr, int E) {
    __shared__ __align__(16) __half2 wt[64 * 64];  // 16 KB; reused by fix/fill
    int b = blockIdx.x, tid = threadIdx.x;
    if (b < FILLB) {
        int* q = (int*)wt;  // Q[l] = sum bsum[0..l-1], l in [0,63]
        int nb = (n + 1023) >> 10;
        if (tid < 64) {
            int v = (tid >= 1 && tid <= nb) ? bsum[tid - 1] : 0;
#pragma unroll
            for (int off = 1; off < 64; off <<= 1) {
                int t = __shfl_up(v, off);
                if ((tid & 63) >= off) v += t;
            }
            q[tid] = v;
        }
        __syncthreads();
        int base = b * 1024;
#pragma unroll
        for (int r = 0; r < 4; ++r) {
            int e = base + r * 256 + tid;
            if (e < E) {
                int c = col[e];
                int qi = (c == 0) ? 0 : ((c - 1) >> 10);  // praw[0]=0, Q[0]=0
                csr[praw[c] + q[qi] + rank[e]] = row[e];
            }
        }
        return;
    }
    if (b < FILLB + FB) {
        int bb = b - FILLB;
        int* red = (int*)wt;
        int partial = 0;
        for (int j = tid; j < bb; j += 256) partial += bsum[j];
        red[tid] = partial;
        __syncthreads();
        for (int off = 128; off > 0; off >>= 1) {
            if (tid < off) red[tid] += red[tid + off];
            __syncthreads();
        }
        int offv = red[0];
        if (offv == 0) return;
#pragma unroll
        for (int r = 0; r < 4; ++r) {
            int i = bb * 1024 + r * 256 + tid;
            if (i < n) rowptr[i + 1] += offv;
        }
        return;
    }
    int gb = b - FILLB - FB;
    gemm1_half(X, W1, scale, Y, M, (gb >> 1) * 64, gb & 1, wt, tid);
}

// Fused agg128 + gemm2. Block = 64 nodes (4 agg sub-phases of 16 nodes),
// then xw2[64,64] = (h_tile @ W2) * dis via MFMA.
// Agg: 4 nodes/wave; invalid edges gather the ZERO ROW n (no guards);
// packed-fp16 pairwise pre-add then fp32 accumulate (~10 VALU ops/edge).
// csr index load pipelined one iter ahead (r19). h_tile XOR-swizzled.
// gemm2 B from global w2h[nn*128+k] (16KB, L1-resident).
__global__ __launch_bounds__(256, 6) void k_agg_gemm(const __half* __restrict__ xw,
                                                     const float* __restrict__ dis,
                                                     const int* __restrict__ rowptr,
                                                     const int* __restrict__ csr,
                                                     const float* __restrict__ bias,
                                                     const __half* __restrict__ w2h,
                                                     __half* __restrict__ Y,  // xw2 [n,64]
                                                     int n) {
    __shared__ __align__(16) half8 htile[64 * 16];   // 16 KB
    int tid = threadIdx.x, b = blockIdx.x;
    int lane = tid & 63, w = tid >> 6;
    int q = lane >> 4, li = lane & 15;
    int qbase = lane & 48;

    const half8* rows = (const half8*)xw;  // 16 half8 per row
    floatx4 bb0 = *(const floatx4*)&bias[li * 8];
    floatx4 bb1 = *(const floatx4*)&bias[li * 8 + 4];

#pragma unroll
    for (int g = 0; g < 4; ++g) {
        int m_loc = g * 16 + (w << 2) + q;     // local row 0..63
        int node = b * 64 + m_loc;
        bool ok = node < n;
        float di = 0.f;
        int beg = 0, end = 0;
        if (ok) {
            di = dis[node];
            beg = rowptr[node];
            end = rowptr[node + 1];
        }
        int dg = end - beg;
        int m1 = max(dg, __shfl(dg, lane ^ 16));
        int mx = max(m1, __shfl(m1, lane ^ 32));  // max over the wave's 4 nodes
        float acc[8] = {};
        if (ok) {
            half8 sf = rows[(size_t)node * 16 + li];
#pragma unroll
            for (int f = 0; f < 8; ++f) acc[f] = (float)sf[f];
        }
        // software-pipelined csr index load; invalid edge -> zero row n
        int ecur = beg + (li & 7);
        int curidx = (0 < mx && ecur < end) ? csr[ecur] : n;
        for (int i = 0; i < mx; i += 8) {
            int enx = beg + i + 8 + (li & 7);
            int nidx = (i + 8 < mx && enx < end) ? csr[enx] : n;
            half8 v[8];
#pragma unroll
            for (int j = 0; j < 8; ++j) {
                int s = __shfl(curidx, qbase + j);
                v[j] = rows[(size_t)s * 16 + li];
            }
#pragma unroll
            for (int p = 0; p < 4; ++p) {
                half8 s2 = v[2 * p] + v[2 * p + 1];  // v_pk_add_f16 x4
#pragma unroll
                for (int f = 0; f < 8; ++f) acc[f] += (float)s2[f];
            }
            curidx = nidx;
        }
        half8 o = {};
        if (ok) {
#pragma unroll
            for (int f = 0; f < 4; ++f) o[f] = (_Float16)fmaxf(acc[f] * di + bb0[f], 0.f);
#pragma unroll
            for (int f = 0; f < 4; ++f) o[4 + f] = (_Float16)fmaxf(acc[4 + f] * di + bb1[f], 0.f);
        }
        htile[m_loc * 16 + (li ^ (m_loc & 7))] = o;
    }
    __syncthreads();

    // GEMM phase: A from htile (swizzled), B from global w2h (L1-resident).
    int col16 = lane & 15, quad = lane >> 4;
    int m_loc = w * 16 + col16;
    floatx4 gacc[4] = {};
#pragma unroll
    for (int ks = 0; ks < 4; ++ks) {
        half8 af = htile[m_loc * 16 + ((ks * 4 + quad) ^ (m_loc & 7))];
        int kblk = ks * 4 + quad;
#pragma unroll
        for (int nt = 0; nt < 4; ++nt) {
            int nn = nt * 16 + col16;
            half8 bf = *(const half8*)(const void*)&w2h[nn * 128 + kblk * 8];
            gacc[nt] = __builtin_amdgcn_mfma_f32_16x16x32_f16(af, bf, gacc[nt], 0, 0, 0);
        }
    }
    int mbase = b * 64 + w * 16 + quad * 4;
    float s[4];
#pragma unroll
    for (int r = 0; r < 4; ++r) s[r] = (mbase + r < n) ? dis[mbase + r] : 0.f;
#pragma unroll
    for (int nt = 0; nt < 4; ++nt) {
#pragma unroll
        for (int r = 0; r < 4; ++r) {
            if (mbase + r < n)
                Y[(size_t)(mbase + r) * 64 + nt * 16 + col16] = __float2half(gacc[nt][r] * s[r]);
        }
    }
}

// F=64: 8 nodes/wave (8 lanes x 16B = one 128B row per gather instr).
// Zero-row + packed-fp16 pair-add as in agg_gemm; csr pipelined.
__global__ __launch_bounds__(256) void k_agg64(const __half* __restrict__ xw,
                                               const float* __restrict__ dis,
                                               const int* __restrict__ rowptr,
                                               const int* __restrict__ csr,
                                               const float* __restrict__ bias,
                                               float* __restrict__ out, int n) {
    int tid = threadIdx.x;
    int lane = tid & 63;
    int o8 = lane >> 3, li = lane & 7;
    int obase = lane & 56;
    int node = blockIdx.x * 32 + ((tid >> 6) << 3) + o8;
    bool ok = node < n;
    float di = 0.f;
    int beg = 0, end = 0;
    if (ok) {
        di = dis[node];
        beg = rowptr[node];
        end = rowptr[node + 1];
    }
    int dg = end - beg;
    int m1 = max(dg, __shfl(dg, lane ^ 8));
    int m2 = max(m1, __shfl(m1, lane ^ 16));
    int mx = max(m2, __shfl(m2, lane ^ 32));  // max over the wave's 8 nodes
    const half8* rows = (const half8*)xw;     // 8 half8 per row
    float acc[8] = {};
    if (ok) {
        half8 sf = rows[(size_t)node * 8 + li];
#pragma unroll
        for (int f = 0; f < 8; ++f) acc[f] = (float)sf[f];
    }
    int ecur = beg + li;
    int curidx = (0 < mx && ecur < end) ? csr[ecur] : n;
    for (int i = 0; i < mx; i += 8) {
        int enx = beg + i + 8 + li;
        int nidx = (i + 8 < mx && enx < end) ? csr[enx] : n;
        half8 v[8];
#pragma unroll
        for (int j = 0; j < 8; ++j) {
            int s = __shfl(curidx, obase + j);
            v[j] = rows[(size_t)s * 8 + li];
        }
#pragma unroll
        for (int p = 0; p < 4; ++p) {
            half8 s2 = v[2 * p] + v[2 * p + 1];  // v_pk_add_f16 x4
#pragma unroll
            for (int f = 0; f < 8; ++f) acc[f] += (float)s2[f];
        }
        curidx = nidx;
    }
    if (ok) {
        floatx4 b0 = *(const floatx4*)&bias[li * 8];
        floatx4 b1 = *(const floatx4*)&bias[li * 8 + 4];
        floatx4 o0, o1;
#pragma unroll
        for (int f = 0; f < 4; ++f) o0[f] = acc[f] * di + b0[f];
#pragma unroll
        for (int f = 0; f < 4; ++f) o1[f] = acc[4 + f] * di + b1[f];
        *(floatx4*)&out[(size_t)node * 64 + li * 8] = o0;
        *(floatx4*)&out[(size_t)node * 64 + li * 8 + 4] = o1;
    }
}

extern "C" void kernel_launch(void* const* d_in, const int* in_sizes, int n_in,
                              void* d_out, int out_size, void* d_ws, size_t ws_size,
                              hipStream_t stream) {
    const float* x  = (const float*)d_in[0];
    const int*   ei = (const int*)d_in[1];
    const float* W1 = (const float*)d_in[2];
    const float* b1 = (const float*)d_in[3];
    const float* W2 = (const float*)d_in[4];
    const float* b2 = (const float*)d_in[5];
    float* out = (float*)d_out;

    const int n = in_sizes[0] / 128;   // 50000
    const int E = in_sizes[1] / 2;     // 800000
    const int* row = ei;
    const int* col = ei + E;
    const int NB = (n + 1023) / 1024;       // scan chunks (fix range)
    const int CB = (E + 255) / 256;
    const int GB = (n + 63) / 64;           // agg_gemm blocks; gemm1 = 2*GB
    const int FILLB = (E + 1023) / 1024;    // fused fill blocks (1024 edges each)

    char* ws = (char*)d_ws;
    size_t off = 0;
    auto alloc = [&](size_t bytes) -> void* {
        void* p = ws + off;
        off += (bytes + 255) & ~(size_t)255;
        return p;
    };
    int*    deg    = (int*)alloc((size_t)n * 4);
    int*    rowptr = (int*)alloc((size_t)(n + 1) * 4);
    int*    praw   = (int*)alloc((size_t)(n + 1) * 4);
    int*    bsum   = (int*)alloc((size_t)NB * 4);
    int*    rank   = (int*)alloc((size_t)E * 4);
    int*    csr    = (int*)alloc((size_t)E * 4);
    float*  dis    = (float*)alloc((size_t)n * 4);
    __half* xw1    = (__half*)alloc((size_t)(n + 1) * 128 * 2);  // +1 zero row
    __half* xw2    = (__half*)alloc((size_t)(n + 1) * 64 * 2);   // +1 zero row
    __half* w2h    = (__half*)alloc((size_t)64 * 128 * 2);       // [64 cols][128 k]
    (void)ws_size;

    hipMemsetAsync(deg, 0, (size_t)n * 4, stream);
    k_count<<<CB, 256, 0, stream>>>(col, deg, rank, E);
    // scan (NB blocks) + 1 spare block: W2->fp16 w2h, zero rows of xw1/xw2
    k_scan_local<<<NB + 1, 1024, 0, stream>>>(deg, rowptr, praw, bsum, dis, n,
                                              W2, w2h, xw1, xw2);
    // fill || fix || gemm1 (N-split) in one 16KB-LDS dispatch; fill first.
    k_fused<<<FILLB + NB + 2 * GB, 256, 0, stream>>>(rowptr, bsum, n, x, W1, dis, xw1,
                                                     n, NB, FILLB, praw, row, col, rank,
                                                     csr, E);
    // agg128 + gemm2 fused: h never touches HBM; B from global w2h.
    k_agg_gemm<<<GB, 256, 0, stream>>>(xw1, dis, rowptr, csr, b1, w2h, xw2, n);
    k_agg64<<<(n + 31) / 32, 256, 0, stream>>>(xw2, dis, rowptr, csr, b2, out, n);
}